// Round 1
// baseline (292.098 us; speedup 1.0000x reference)
//
#include <hip/hip_runtime.h>

typedef unsigned short u16;
typedef u16   u16x8 __attribute__((ext_vector_type(8)));
typedef __bf16 bf16x8 __attribute__((ext_vector_type(8)));
typedef float f32x4 __attribute__((ext_vector_type(4)));

__device__ __forceinline__ u16 f2b(float f){ __bf16 h=(__bf16)f; return __builtin_bit_cast(u16,h); }

__device__ __forceinline__ f32x4 mfma16(u16x8 a, u16x8 b, f32x4 c){
  return __builtin_amdgcn_mfma_f32_16x16x32_bf16(
      __builtin_bit_cast(bf16x8,a), __builtin_bit_cast(bf16x8,b), c, 0,0,0);
}

__device__ __forceinline__ void gl2lds16(const u16* g, u16* l){
  __builtin_amdgcn_global_load_lds((const __attribute__((address_space(1))) void*)g,
                                   (__attribute__((address_space(3))) void*)l, 16, 0, 0);
}

// ---------------- LayerNorm: fp32 [4096,1024] -> bf16 xn ----------------
__global__ __launch_bounds__(256) void ln_kernel(const float* __restrict__ x,
                                                 const float* __restrict__ gamma,
                                                 const float* __restrict__ beta,
                                                 u16* __restrict__ xn){
  const int row = blockIdx.x, t = threadIdx.x;
  const float4 v = ((const float4*)(x + (size_t)row*1024))[t];
  float s  = v.x+v.y+v.z+v.w;
  float sq = v.x*v.x+v.y*v.y+v.z*v.z+v.w*v.w;
  for (int m=1;m<64;m<<=1){ s += __shfl_xor(s,m); sq += __shfl_xor(sq,m); }
  __shared__ float red[8];
  const int w=t>>6, l=t&63;
  if(l==0){ red[w]=s; red[4+w]=sq; }
  __syncthreads();
  const float S  = red[0]+red[1]+red[2]+red[3];
  const float SQ = red[4]+red[5]+red[6]+red[7];
  const float mu = S*(1.f/1024.f);
  const float var= SQ*(1.f/1024.f)-mu*mu;
  const float rs = rsqrtf(var+1e-5f);
  const float4 g4=((const float4*)gamma)[t], b4=((const float4*)beta)[t];
  u16 o0=f2b((v.x-mu)*rs*g4.x+b4.x);
  u16 o1=f2b((v.y-mu)*rs*g4.y+b4.y);
  u16 o2=f2b((v.z-mu)*rs*g4.z+b4.z);
  u16 o3=f2b((v.w-mu)*rs*g4.w+b4.w);
  uint2 p; p.x=(unsigned)o0|((unsigned)o1<<16); p.y=(unsigned)o2|((unsigned)o3<<16);
  ((uint2*)(xn + (size_t)row*1024))[t]=p;
}

// ------------- transpose-convert fp32 [R][C] -> bf16 [C][R] -------------
__global__ __launch_bounds__(256) void wtrans_kernel(const float* __restrict__ in,
                                                     u16* __restrict__ out, int R, int C){
  __shared__ float tile[64][65];
  const int c0=blockIdx.x*64, r0=blockIdx.y*64, t=threadIdx.x;
  {
    const int r=t>>2, cc=t&3;
    const float* gp = in + (size_t)(r0+r)*C + c0 + cc*16;
    #pragma unroll
    for(int i=0;i<4;i++){
      float4 f=((const float4*)gp)[i];
      tile[r][cc*16+i*4+0]=f.x; tile[r][cc*16+i*4+1]=f.y;
      tile[r][cc*16+i*4+2]=f.z; tile[r][cc*16+i*4+3]=f.w;
    }
  }
  __syncthreads();
  const int c=t>>2, rc=t&3;
  u16x8 a,b;
  #pragma unroll
  for(int i=0;i<8;i++) a[i]=f2b(tile[rc*16+i][c]);
  #pragma unroll
  for(int i=0;i<8;i++) b[i]=f2b(tile[rc*16+8+i][c]);
  u16* op = out + (size_t)(c0+c)*R + r0 + rc*16;
  *(u16x8*)op=a; *(u16x8*)(op+8)=b;
}

// --------- V transpose: kv bf16 [b*2048][2048] (cols 1024..) -> Vt [b][h][64][2048]
__global__ __launch_bounds__(256) void vtrans_kernel(const u16* __restrict__ kv,
                                                     u16* __restrict__ vt){
  __shared__ u16 tile[64][72];
  const int tok0=blockIdx.x*64, h=blockIdx.y, bb=blockIdx.z, t=threadIdx.x;
  {
    const int r=t>>2, cc=t&3;
    const u16* gp = kv + (size_t)(bb*2048 + tok0 + r)*2048 + 1024 + h*64 + cc*16;
    *(u16x8*)&tile[r][cc*16]   = *(const u16x8*)gp;
    *(u16x8*)&tile[r][cc*16+8] = *(const u16x8*)(gp+8);
  }
  __syncthreads();
  const int d=t>>2, tc=t&3;
  u16x8 a,b;
  #pragma unroll
  for(int i=0;i<8;i++) a[i]=tile[tc*16+i][d];
  #pragma unroll
  for(int i=0;i<8;i++) b[i]=tile[tc*16+8+i][d];
  u16* op = vt + ((size_t)(bb*16+h)*64 + d)*2048 + tok0 + tc*16;
  *(u16x8*)op=a; *(u16x8*)(op+8)=b;
}

// --------------- GEMM: A bf16 [M,K] x Bt bf16 [N,K] -> out -------------
// OUT_F32=0: bf16 out (scaled); OUT_F32=1: fp32 out + bias
template<int OUT_F32>
__global__ __launch_bounds__(256) void gemm_bt_kernel(const u16* __restrict__ A,
    const u16* __restrict__ Bt, u16* __restrict__ outB, float* __restrict__ outF,
    const float* __restrict__ bias, float scale, int M, int N, int K){
  __shared__ u16 As[128*64];
  __shared__ u16 Bs[128*64];
  const int t=threadIdx.x, w=t>>6, l=t&63, qd=l>>4, ln=l&15;
  const int m0=blockIdx.y*128, n0=blockIdx.x*128;
  const int wm=(w>>1)*64, wn=(w&1)*64;
  f32x4 acc[4][4] = {};
  const int nK = K>>6;
  for(int kt=0; kt<nK; kt++){
    const int k0=kt*64;
    #pragma unroll
    for(int p=0;p<4;p++){
      const int cid=p*256+t, r=cid>>3, pc=cid&7, g=pc^(r&7);
      gl2lds16(A + (size_t)(m0+r)*K + k0 + g*8, &As[(p*256 + (t&192))*8]);
    }
    #pragma unroll
    for(int p=0;p<4;p++){
      const int cid=p*256+t, r=cid>>3, pc=cid&7, g=pc^(r&7);
      gl2lds16(Bt + (size_t)(n0+r)*K + k0 + g*8, &Bs[(p*256 + (t&192))*8]);
    }
    __syncthreads();
    #pragma unroll
    for(int ks=0;ks<2;ks++){
      u16x8 af[4], bf[4];
      #pragma unroll
      for(int mt=0;mt<4;mt++){
        const int m=wm+mt*16+ln, kc=ks*4+qd, pcc=kc^(m&7);
        af[mt]=*(const u16x8*)&As[m*64 + pcc*8];
      }
      #pragma unroll
      for(int nt=0;nt<4;nt++){
        const int n=wn+nt*16+ln, kc=ks*4+qd, pcc=kc^(n&7);
        bf[nt]=*(const u16x8*)&Bs[n*64 + pcc*8];
      }
      #pragma unroll
      for(int mt=0;mt<4;mt++)
        #pragma unroll
        for(int nt=0;nt<4;nt++)
          acc[mt][nt]=mfma16(af[mt],bf[nt],acc[mt][nt]);
    }
    __syncthreads();
  }
  #pragma unroll
  for(int mt=0;mt<4;mt++)
    #pragma unroll
    for(int rr=0;rr<4;rr++){
      const int row = m0+wm+mt*16+qd*4+rr;
      #pragma unroll
      for(int nt=0;nt<4;nt++){
        const int col = n0+wn+nt*16+ln;
        const float v = acc[mt][nt][rr]*scale;
        if(OUT_F32) outF[(size_t)row*N+col]=v+bias[col];
        else        outB[(size_t)row*N+col]=f2b(v);
      }
    }
}

// --------------------------- flash attention ---------------------------
// Q bf16 [b,2048,1024] (scale*log2e folded), K = kv cols 0..1023 (stride 2048),
// Vt bf16 [b,h,64,2048], O bf16 [b,2048,1024]
__global__ __launch_bounds__(256) void attn_kernel(const u16* __restrict__ Q,
    const u16* __restrict__ Kb, const u16* __restrict__ Vt, u16* __restrict__ O){
  __shared__ u16 Qs[64*72];
  __shared__ u16 Ks[128*72];
  __shared__ u16 Vs[64*136];
  __shared__ u16 Ps[4][16*136];
  const int qt=blockIdx.x, h=blockIdx.y, bb=blockIdx.z;
  const int t=threadIdx.x, w=t>>6, l=t&63, qd=l>>4, ln=l&15;
  const size_t baseQ = (size_t)bb*2048*1024 + h*64;
  const size_t baseK = (size_t)bb*2048*2048 + h*64;
  const size_t baseV = ((size_t)(bb*16+h)*64)*2048;
  {
    const int r=t>>2, cc=t&3;
    const u16* gp = Q + baseQ + (size_t)(qt*64+r)*1024 + cc*16;
    *(u16x8*)&Qs[r*72+cc*16]   = *(const u16x8*)gp;
    *(u16x8*)&Qs[r*72+cc*16+8] = *(const u16x8*)(gp+8);
  }
  float m_i[4], l_i[4];
  f32x4 o_acc[4] = {};
  #pragma unroll
  for(int r=0;r<4;r++){ m_i[r]=-1e30f; l_i[r]=0.f; }

  for(int j0=0;j0<2048;j0+=128){
    __syncthreads();
    #pragma unroll
    for(int p=0;p<2;p++){
      const int idx=p*256+t, r=idx>>2, cc=idx&3;
      const u16* gp = Kb + baseK + (size_t)(j0+r)*2048 + cc*16;
      *(u16x8*)&Ks[r*72+cc*16]   = *(const u16x8*)gp;
      *(u16x8*)&Ks[r*72+cc*16+8] = *(const u16x8*)(gp+8);
    }
    #pragma unroll
    for(int p=0;p<2;p++){
      const int idx=p*256+t, d=idx>>3, jc=idx&7;
      const u16* gp = Vt + baseV + (size_t)d*2048 + j0 + jc*16;
      *(u16x8*)&Vs[d*136+jc*16]   = *(const u16x8*)gp;
      *(u16x8*)&Vs[d*136+jc*16+8] = *(const u16x8*)(gp+8);
    }
    __syncthreads();

    f32x4 s[8] = {};
    #pragma unroll
    for(int ks=0;ks<2;ks++){
      const u16x8 af = *(const u16x8*)&Qs[(w*16+ln)*72 + ks*32 + qd*8];
      #pragma unroll
      for(int jt=0;jt<8;jt++){
        const u16x8 bf = *(const u16x8*)&Ks[(jt*16+ln)*72 + ks*32 + qd*8];
        s[jt]=mfma16(af,bf,s[jt]);
      }
    }
    #pragma unroll
    for(int rr=0;rr<4;rr++){
      float mx=s[0][rr];
      #pragma unroll
      for(int jt=1;jt<8;jt++) mx=fmaxf(mx,s[jt][rr]);
      for(int msk=1;msk<16;msk<<=1) mx=fmaxf(mx,__shfl_xor(mx,msk));
      const float mnew=fmaxf(m_i[rr],mx);
      const float alpha=exp2f(m_i[rr]-mnew);
      m_i[rr]=mnew;
      float sum=0.f;
      #pragma unroll
      for(int jt=0;jt<8;jt++){ const float pv=exp2f(s[jt][rr]-mnew); s[jt][rr]=pv; sum+=pv; }
      for(int msk=1;msk<16;msk<<=1) sum+=__shfl_xor(sum,msk);
      l_i[rr]=l_i[rr]*alpha+sum;
      #pragma unroll
      for(int dt=0;dt<4;dt++) o_acc[dt][rr]*=alpha;
    }
    #pragma unroll
    for(int jt=0;jt<8;jt++)
      #pragma unroll
      for(int rr=0;rr<4;rr++)
        Ps[w][(qd*4+rr)*136 + jt*16 + ln] = f2b(s[jt][rr]);
    #pragma unroll
    for(int js=0;js<4;js++){
      const u16x8 pf=*(const u16x8*)&Ps[w][ln*136 + js*32 + qd*8];
      #pragma unroll
      for(int dt=0;dt<4;dt++){
        const u16x8 vf=*(const u16x8*)&Vs[(dt*16+ln)*136 + js*32 + qd*8];
        o_acc[dt]=mfma16(pf,vf,o_acc[dt]);
      }
    }
  }
  #pragma unroll
  for(int dt=0;dt<4;dt++)
    #pragma unroll
    for(int rr=0;rr<4;rr++){
      const int row = qt*64 + w*16 + qd*4 + rr;
      const float v = o_acc[dt][rr]/l_i[rr];
      O[baseQ + (size_t)row*1024 + dt*16 + ln] = f2b(v);
    }
}

extern "C" void kernel_launch(void* const* d_in, const int* in_sizes, int n_in,
                              void* d_out, int out_size, void* d_ws, size_t ws_size,
                              hipStream_t stream) {
  const float* x     = (const float*)d_in[0];
  const float* w_q   = (const float*)d_in[1];
  const float* w_kv  = (const float*)d_in[2];
  const float* w_out = (const float*)d_in[3];
  const float* b_out = (const float*)d_in[4];
  const float* gamma = (const float*)d_in[5];
  const float* beta  = (const float*)d_in[6];
  float* out = (float*)d_out;

  char* ws=(char*)d_ws;
  size_t off=0;
  u16* xn   =(u16*)(ws+off); off += (size_t)4096*1024*2;
  u16* wqt  =(u16*)(ws+off); off += (size_t)1024*1024*2;
  u16* wkvt =(u16*)(ws+off); off += (size_t)2048*1024*2;
  u16* woutt=(u16*)(ws+off); off += (size_t)1024*1024*2;
  u16* qb   =(u16*)(ws+off); off += (size_t)4096*1024*2;
  u16* kvb  =(u16*)(ws+off); off += (size_t)4096*2048*2;
  u16* vtb  =(u16*)(ws+off); off += (size_t)4096*1024*2;
  u16* ob   =(u16*)(ws+off); off += (size_t)4096*1024*2;

  ln_kernel<<<4096,256,0,stream>>>(x,gamma,beta,xn);
  wtrans_kernel<<<dim3(16,16),256,0,stream>>>(w_q,  wqt,  1024,1024);
  wtrans_kernel<<<dim3(32,16),256,0,stream>>>(w_kv, wkvt, 1024,2048);
  wtrans_kernel<<<dim3(16,16),256,0,stream>>>(w_out,woutt,1024,1024);

  const float SCALE_Q = 0.125f*1.4426950408889634f; // fold 1/sqrt(d) * log2(e)
  gemm_bt_kernel<0><<<dim3(8,32), 256,0,stream>>>(xn,wqt, qb, nullptr,nullptr,SCALE_Q,4096,1024,1024);
  gemm_bt_kernel<0><<<dim3(16,32),256,0,stream>>>(xn,wkvt,kvb,nullptr,nullptr,1.f,    4096,2048,1024);
  vtrans_kernel<<<dim3(32,16,2),256,0,stream>>>(kvb,vtb);
  attn_kernel<<<dim3(32,16,2),256,0,stream>>>(qb,kvb,vtb,ob);
  gemm_bt_kernel<1><<<dim3(8,32), 256,0,stream>>>(ob,woutt,nullptr,out,b_out,1.f,4096,1024,1024);
}